// Round 4
// baseline (1832.530 us; speedup 1.0000x reference)
//
#include <hip/hip_runtime.h>
#include <hip/hip_bf16.h>

typedef __hip_bfloat16 bf16;
typedef __attribute__((ext_vector_type(8))) short s16x8;   // 8 bf16 (4 VGPR) MFMA A/B frag
typedef __attribute__((ext_vector_type(4))) float f32x4;   // MFMA C/D frag

__device__ __forceinline__ float b2f(bf16 x) { return __bfloat162float(x); }
__device__ __forceinline__ bf16 f2b(float x) { return __float2bfloat16(x); }

__device__ __forceinline__ void gld16(const void* g, void* l) {
  __builtin_amdgcn_global_load_lds((const __attribute__((address_space(1))) unsigned int*)g,
                                   (__attribute__((address_space(3))) unsigned int*)l,
                                   16, 0, 0);
}

// ---------------------------------------------------------------------------
// sentinel: unmistakable absmax if workspace too small (f32 out)
__global__ __launch_bounds__(256) void fill_sentinel(float* out, int n) {
  int idx = blockIdx.x * 256 + threadIdx.x;
  if (idx < n) out[idx] = 100.0f;
}

__global__ __launch_bounds__(64) void zero_zb(bf16* zb) {
  zb[threadIdx.x * 2] = f2b(0.f);
  zb[threadIdx.x * 2 + 1] = f2b(0.f);
}

// ---------------------------------------------------------------------------
// pack conv weights (f32 -> bf16): wpN[s][o][c]; wnp[p][t][ot][c][m]
__global__ __launch_bounds__(256) void pack_w(const float* __restrict__ c0w,
                                              const float* __restrict__ c1w,
                                              const float* __restrict__ lw,
                                              bf16* wp0, bf16* wp1, bf16* wp2, bf16* wnp) {
  const int SEG = 9 * 256 * 256;
  int idx = blockIdx.x * 256 + threadIdx.x;
  if (idx < 3 * SEG) {
    int which = idx / SEG, r = idx % SEG;
    int s = r >> 16, o = (r >> 8) & 255, c = r & 255;
    int ky = s / 3, kx = s - 3 * ky;
    if (which == 0)      wp0[r] = f2b(c0w[(((size_t)o * 768 + 256 + c) * 3 + ky) * 3 + kx]);
    else if (which == 1) wp1[r] = f2b(c1w[(((size_t)o * 256 + c) * 3 + ky) * 3 + kx]);
    else                 wp2[r] = f2b(lw [(((size_t)o * 256 + c) * 3 + ky) * 3 + kx]);
  } else {
    int r = idx - 3 * SEG;             // [p][t][ot][c][m]
    int m = r & 255, c = (r >> 8) & 255, tt = r >> 16;
    int ot = tt % 3, t2 = (tt / 3) % 3, p = tt / 9;
    int ky, kx, cin;
    if (p == 0) { kx = t2; ky = ot; cin = c; }        // node_i block
    else        { ky = t2; kx = ot; cin = 512 + c; }  // node_j block
    wnp[r] = f2b(c0w[(((size_t)m * 768 + cin) * 3 + ky) * 3 + kx]);
  }
}

// ---------------------------------------------------------------------------
// adapter 1x1 (one batch): E[i][j][m] = sum_c aw[m][c]*e[i][j][c] + ab[m]  (f32 in, bf16 out)
__global__ __launch_bounds__(256) void adapter_k(const float* __restrict__ e,
                                                 const float* __restrict__ aw,
                                                 const float* __restrict__ ab,
                                                 bf16* __restrict__ E) {
  int i = blockIdx.x;
  int m = threadIdx.x;
  __shared__ float se[256 * 7];
  const size_t rb = (size_t)i * (256 * 7);
  for (int idx = m; idx < 256 * 7; idx += 256) se[idx] = e[rb + idx];
  __syncthreads();
  float w[7];
#pragma unroll
  for (int c = 0; c < 7; ++c) w[c] = aw[m * 7 + c];
  float bias = ab[m];
  bf16* ob = E + (size_t)i * 65536 + m;
  for (int j = 0; j < 256; ++j) {
    const float* ej = se + j * 7;
    float a = bias;
#pragma unroll
    for (int c = 0; c < 7; ++c) a += w[c] * ej[c];
    ob[(size_t)j * 256] = f2b(a);
  }
}

// ---------------------------------------------------------------------------
// node terms: TT[p][t][pos][m] = sum_{ot,c} wnp[p][t][ot][c][m]*nd_pad[pos+ot-1][c]
template <typename T>
__global__ __launch_bounds__(256) void node_terms(const T* __restrict__ nd,
                                                  const bf16* __restrict__ wnp,
                                                  float* __restrict__ TT) {
  int bid = blockIdx.x;        // p(2) * t(3) * chunk(8) = 48
  int chunk = bid & 7;
  int t = (bid >> 3) % 3;
  int p = bid / 24;
  int tid = threadIdx.x;
  __shared__ float snd[34][256];
  int pos0 = chunk * 32;
  for (int idx = tid; idx < 34 * 256; idx += 256) {
    int r = idx >> 8, c = idx & 255;
    int gp = pos0 - 1 + r;
    snd[r][c] = (gp >= 0 && gp < 256) ? (float)nd[(size_t)gp * 256 + c] : 0.f;
  }
  __syncthreads();
  float acc[32];
#pragma unroll
  for (int ii = 0; ii < 32; ++ii) acc[ii] = 0.f;
  const bf16* wb = wnp + (size_t)((p * 3 + t) * 3) * 65536 + tid;
  for (int c = 0; c < 256; ++c) {
    float w0 = b2f(wb[(size_t)c * 256]);
    float w1 = b2f(wb[(size_t)(65536 + c * 256)]);
    float w2 = b2f(wb[(size_t)(2 * 65536 + c * 256)]);
#pragma unroll
    for (int r = 0; r < 34; ++r) {
      float v = snd[r][c];
      if (r < 32)           acc[r]     += w0 * v;  // ot=0
      if (r >= 1 && r < 33) acc[r - 1] += w1 * v;  // ot=1
      if (r >= 2)           acc[r - 2] += w2 * v;  // ot=2
    }
  }
  float* o = TT + (((size_t)(p * 3 + t) * 256 + pos0) * 256) + tid;
#pragma unroll
  for (int ii = 0; ii < 32; ++ii) o[(size_t)ii * 256] = acc[ii];
}

// ---------------------------------------------------------------------------
// implicit-GEMM 3x3 conv (one batch), 256->256 ch, act [i][j][m] bf16, zero pad.
// EPI: add node terms (+ boundary masks). F32OUT: write f32 (final edge output).
template <int EPI, int F32OUT>
__global__ __launch_bounds__(256, 2)
void conv3x3_k(const bf16* __restrict__ inb, const bf16* __restrict__ wpack,
               const float* __restrict__ bias, void* __restrict__ outv,
               const float* __restrict__ TT, const bf16* __restrict__ zbuf) {
  __shared__ __align__(16) char lB[16384];  // input  [128 px][64 ch] (swizzled)
  __shared__ __align__(16) char lA[16384];  // weight [128 o ][64 ch] (swizzled)
  const int bid = blockIdx.x;               // 1024 = ob(2) * jb(2) * i(256)
  const int ob = bid & 1, jb = (bid >> 1) & 1, i = bid >> 2;
  const int tid = threadIdx.x;
  const int lane = tid & 63, wid = tid >> 6;
  const int wr = wid >> 1, wc = wid & 1;
  const int lo = lane & 15, hi = lane >> 4;

  f32x4 acc[4][4];
  const f32x4 z = {0.f, 0.f, 0.f, 0.f};
#pragma unroll
  for (int mi = 0; mi < 4; ++mi)
#pragma unroll
    for (int ni = 0; ni < 4; ++ni) acc[mi][ni] = z;

  const int xS = tid >> 3;   // staging pixel (row) within 32-row chunk
  const int Gs = tid & 7;    // staging 16B-granule slot
  for (int s = 0; s < 9; ++s) {
    const int ky = s / 3, kx = s - 3 * ky;
    const int r = i + ky - 1;
    if (r < 0 || r > 255) continue;           // block-uniform zero row tap
    const size_t rowbase = (size_t)r * 65536;
    const int colbase = jb * 128 + kx - 1;
    const size_t wbase = ((size_t)s * 256 + ob * 128) * 256;
    for (int cc = 0; cc < 4; ++cc) {
      __syncthreads();                        // prior MFMA reads drained
      const int cb = cc * 64;
#pragma unroll
      for (int ch = 0; ch < 4; ++ch) {
        const int x = ch * 32 + xS;
        const int c = colbase + x;
        const int sw = (Gs ^ (x & 7)) << 3;   // pre-swizzled source granule
        const int ldst = (ch * 256 + wid * 64) << 4;  // wave-uniform LDS dest
        const bf16* srcB = (c >= 0 && c <= 255)
            ? inb + rowbase + ((size_t)c << 8) + cb + sw
            : zbuf + sw;                       // OOB column -> zeros
        gld16(srcB, lB + ldst);
        gld16(wpack + wbase + ((size_t)x << 8) + cb + sw, lA + ldst);
      }
      __syncthreads();                        // staging visible (vmcnt drained)
#pragma unroll
      for (int kk = 0; kk < 2; ++kk) {
        s16x8 af[4], bfr[4];
        const int g0 = kk * 4 + hi;
        const int gx = (g0 ^ (lo & 7)) << 4;
#pragma unroll
        for (int mi = 0; mi < 4; ++mi) {
          const int x = wr * 64 + mi * 16 + lo;
          af[mi] = *(const s16x8*)(lB + x * 128 + gx);
        }
#pragma unroll
        for (int ni = 0; ni < 4; ++ni) {
          const int x = wc * 64 + ni * 16 + lo;
          bfr[ni] = *(const s16x8*)(lA + x * 128 + gx);
        }
#pragma unroll
        for (int mi = 0; mi < 4; ++mi)
#pragma unroll
          for (int ni = 0; ni < 4; ++ni)
            acc[mi][ni] = __builtin_amdgcn_mfma_f32_16x16x32_bf16(af[mi], bfr[ni], acc[mi][ni], 0, 0, 0);
      }
    }
  }

  // epilogue: D col(lane&15)->o, row((lane>>4)*4+r)->pixel j
  const int o_base = ob * 128 + wc * 64 + lo;
  const int j_base = jb * 128 + wr * 64 + hi * 4;
  bf16* orow = (bf16*)outv + (size_t)i * 65536;
  float* orowf = (float*)outv + (size_t)i * 65536;
#pragma unroll
  for (int ni = 0; ni < 4; ++ni) {
    const int o = o_base + ni * 16;
    const float bs = bias[o];
    float ni0 = 0.f, ni1 = 0.f, ni2 = 0.f;
    if (EPI) {
      const float* TI = TT + (size_t)i * 256 + o;     // p=0 (node_i), t=kx
      ni0 = TI[0]; ni1 = TI[65536]; ni2 = TI[2 * 65536];
    }
#pragma unroll
    for (int mi = 0; mi < 4; ++mi) {
#pragma unroll
      for (int r = 0; r < 4; ++r) {
        const int j = j_base + mi * 16 + r;
        float v = acc[mi][ni][r] + bs;
        if (EPI) {
          v += ni1 + (j > 0 ? ni0 : 0.f) + (j < 255 ? ni2 : 0.f);
          const float* TJ = TT + (size_t)3 * 65536 + (size_t)j * 256 + o;  // p=1, t=ky
          float nj0 = TJ[0], nj1 = TJ[65536], nj2 = TJ[2 * 65536];
          v += nj1 + (i > 0 ? nj0 : 0.f) + (i < 255 ? nj2 : 0.f);
        }
        v = fmaxf(v, 0.f);
        if (F32OUT) orowf[(size_t)j * 256 + o] = v;
        else        orow[(size_t)j * 256 + o] = f2b(v);
      }
    }
  }
}

// ---------------------------------------------------------------------------
// fused: att = leaky(1x1(feat)); coeff = softmax_j; nd[i][m] = sum_j coeff*feat
// F32OUT: write f32 final node output, else bf16 ND scratch.
template <int F32OUT>
__global__ __launch_bounds__(256) void att_wsum(const bf16* __restrict__ feat,
                                                const float* __restrict__ aw,
                                                const float* __restrict__ ab,
                                                bf16* __restrict__ ndb,
                                                float* __restrict__ ndf) {
  int i = blockIdx.x;
  int tid = threadIdx.x, lane = tid & 63, w = tid >> 6;
  __shared__ float s_aw[256];
  __shared__ float s_att[256];
  __shared__ float s_red[8];
  s_aw[tid] = aw[tid];
  __syncthreads();
  float a0 = s_aw[lane * 4], a1 = s_aw[lane * 4 + 1];
  float a2 = s_aw[lane * 4 + 2], a3 = s_aw[lane * 4 + 3];
  const bf16* fb = feat + (size_t)i * 65536;
  float abv = ab[0];
  for (int jj = 0; jj < 64; ++jj) {
    int j = w * 64 + jj;
    const bf16* f = fb + (size_t)j * 256 + lane * 4;
    float v = a0 * b2f(f[0]) + a1 * b2f(f[1]) + a2 * b2f(f[2]) + a3 * b2f(f[3]);
#pragma unroll
    for (int mk = 32; mk; mk >>= 1) v += __shfl_xor(v, mk);
    if (lane == 0) { float a = v + abv; s_att[j] = a > 0.f ? a : 0.01f * a; }
  }
  __syncthreads();
  float x = s_att[tid];
  float mx = x;
#pragma unroll
  for (int mk = 32; mk; mk >>= 1) mx = fmaxf(mx, __shfl_xor(mx, mk));
  if (lane == 0) s_red[w] = mx;
  __syncthreads();
  mx = fmaxf(fmaxf(s_red[0], s_red[1]), fmaxf(s_red[2], s_red[3]));
  float e = expf(x - mx);
  float sm = e;
#pragma unroll
  for (int mk = 32; mk; mk >>= 1) sm += __shfl_xor(sm, mk);
  if (lane == 0) s_red[4 + w] = sm;
  __syncthreads();
  sm = s_red[4] + s_red[5] + s_red[6] + s_red[7];
  __syncthreads();
  s_att[tid] = e / sm;
  __syncthreads();
  float acc = 0.f;
  for (int j = 0; j < 256; ++j) acc += s_att[j] * b2f(fb[(size_t)j * 256 + tid]);
  if (F32OUT) ndf[(size_t)i * 256 + tid] = acc;
  else        ndb[(size_t)i * 256 + tid] = f2b(acc);
}

// ---------------------------------------------------------------------------
extern "C" void kernel_launch(void* const* d_in, const int* in_sizes, int n_in,
                              void* d_out, int out_size, void* d_ws, size_t ws_size,
                              hipStream_t stream) {
  const float* edge_feats = (const float*)d_in[0];
  const float* node_feats = (const float*)d_in[1];
  const float* adapter_w  = (const float*)d_in[2];
  const float* adapter_b  = (const float*)d_in[3];
  const float* conv0_w    = (const float*)d_in[4];
  const float* conv0_b    = (const float*)d_in[5];
  const float* conv1_w    = (const float*)d_in[6];
  const float* conv1_b    = (const float*)d_in[7];
  const float* last_w     = (const float*)d_in[8];
  const float* last_b     = (const float*)d_in[9];
  const float* att_w      = (const float*)d_in[10];
  const float* att_b      = (const float*)d_in[11];
  float* out = (float*)d_out;

  char* ws = (char*)d_ws;
  size_t off = 0;
  bf16* Q   = (bf16*)(ws + off); off += (size_t)256 * 256 * 256 * 2;      // 33,554,432
  bf16* WP0 = (bf16*)(ws + off); off += (size_t)9 * 65536 * 2;
  bf16* WP1 = (bf16*)(ws + off); off += (size_t)9 * 65536 * 2;
  bf16* WP2 = (bf16*)(ws + off); off += (size_t)9 * 65536 * 2;
  bf16* WNP = (bf16*)(ws + off); off += (size_t)18 * 65536 * 2;           //  2,359,296
  float* TT = (float*)(ws + off); off += (size_t)2 * 3 * 65536 * 4;       //  1,572,864
  bf16* ND  = (bf16*)(ws + off); off += (size_t)65536 * 2;                //    131,072
  bf16* ZB  = (bf16*)(ws + off); off += 256;                              // known-safe total 41,156,864
  if (ws_size < off) {
    fill_sentinel<<<(out_size + 255) / 256, 256, 0, stream>>>(out, out_size);
    return;
  }

  zero_zb<<<1, 64, 0, stream>>>(ZB);
  pack_w<<<11520, 256, 0, stream>>>(conv0_w, conv1_w, last_w, WP0, WP1, WP2, WNP);

  for (int b = 0; b < 2; ++b) {
    // P: bf16 scratch inside the (f32) edge-out region of batch b (first 32MB of 64MB)
    bf16* P = (bf16*)(out + 131072 + (size_t)b * 16777216);
    float* edge_out = out + 131072 + (size_t)b * 16777216;
    float* node_out = out + (size_t)b * 65536;
    const float* eb = edge_feats + (size_t)b * 458752;
    const float* nb = node_feats + (size_t)b * 65536;

    adapter_k<<<256, 256, 0, stream>>>(eb, adapter_w, adapter_b, P);                  // E  @ P
    // block 1
    node_terms<float><<<48, 256, 0, stream>>>(nb, WNP, TT);
    conv3x3_k<1, 0><<<1024, 256, 0, stream>>>(P, WP0, conv0_b, Q, TT, ZB);            // A  @ Q
    conv3x3_k<0, 0><<<1024, 256, 0, stream>>>(Q, WP1, conv1_b, P, nullptr, ZB);       // B  @ P
    att_wsum<0><<<256, 256, 0, stream>>>(P, att_w, att_b, ND, nullptr);               // nd1 @ ND
    conv3x3_k<0, 0><<<1024, 256, 0, stream>>>(P, WP2, last_b, Q, nullptr, ZB);        // C  @ Q
    // block 2
    node_terms<bf16><<<48, 256, 0, stream>>>(ND, WNP, TT);
    conv3x3_k<1, 0><<<1024, 256, 0, stream>>>(Q, WP0, conv0_b, P, TT, ZB);            // D  @ P
    conv3x3_k<0, 0><<<1024, 256, 0, stream>>>(P, WP1, conv1_b, Q, nullptr, ZB);       // E2 @ Q
    att_wsum<1><<<256, 256, 0, stream>>>(Q, att_w, att_b, nullptr, node_out);         // node out (f32)
    conv3x3_k<0, 1><<<1024, 256, 0, stream>>>(Q, WP2, last_b, edge_out, nullptr, ZB); // edge out (f32)
  }
}

// Round 5
// 1503.993 us; speedup vs baseline: 1.2184x; 1.2184x over previous
//
#include <hip/hip_runtime.h>
#include <hip/hip_bf16.h>

typedef __hip_bfloat16 bf16;
typedef __attribute__((ext_vector_type(8))) short s16x8;   // 8 bf16 (4 VGPR) MFMA A/B frag
typedef __attribute__((ext_vector_type(4))) float f32x4;   // MFMA C/D frag

__device__ __forceinline__ float b2f(bf16 x) { return __bfloat162float(x); }
__device__ __forceinline__ bf16 f2b(float x) { return __float2bfloat16(x); }

__device__ __forceinline__ void gld16(const void* g, void* l) {
  __builtin_amdgcn_global_load_lds((const __attribute__((address_space(1))) unsigned int*)g,
                                   (__attribute__((address_space(3))) unsigned int*)l,
                                   16, 0, 0);
}

// ---------------------------------------------------------------------------
// sentinel: unmistakable absmax if workspace too small (f32 out)
__global__ __launch_bounds__(256) void fill_sentinel(float* out, int n) {
  int idx = blockIdx.x * 256 + threadIdx.x;
  if (idx < n) out[idx] = 100.0f;
}

__global__ __launch_bounds__(64) void zero_zb(bf16* zb) {
  zb[threadIdx.x * 2] = f2b(0.f);
  zb[threadIdx.x * 2 + 1] = f2b(0.f);
}

// ---------------------------------------------------------------------------
// pack conv weights (f32 -> bf16): wpN[s][o][c]; wnp[p][t][ot][c][m]
__global__ __launch_bounds__(256) void pack_w(const float* __restrict__ c0w,
                                              const float* __restrict__ c1w,
                                              const float* __restrict__ lw,
                                              bf16* wp0, bf16* wp1, bf16* wp2, bf16* wnp) {
  const int SEG = 9 * 256 * 256;
  int idx = blockIdx.x * 256 + threadIdx.x;
  if (idx < 3 * SEG) {
    int which = idx / SEG, r = idx % SEG;
    int s = r >> 16, o = (r >> 8) & 255, c = r & 255;
    int ky = s / 3, kx = s - 3 * ky;
    if (which == 0)      wp0[r] = f2b(c0w[(((size_t)o * 768 + 256 + c) * 3 + ky) * 3 + kx]);
    else if (which == 1) wp1[r] = f2b(c1w[(((size_t)o * 256 + c) * 3 + ky) * 3 + kx]);
    else                 wp2[r] = f2b(lw [(((size_t)o * 256 + c) * 3 + ky) * 3 + kx]);
  } else {
    int r = idx - 3 * SEG;             // [p][t][ot][c][m]
    int m = r & 255, c = (r >> 8) & 255, tt = r >> 16;
    int ot = tt % 3, t2 = (tt / 3) % 3, p = tt / 9;
    int ky, kx, cin;
    if (p == 0) { kx = t2; ky = ot; cin = c; }        // node_i block
    else        { ky = t2; kx = ot; cin = 512 + c; }  // node_j block
    wnp[r] = f2b(c0w[(((size_t)m * 768 + cin) * 3 + ky) * 3 + kx]);
  }
}

// ---------------------------------------------------------------------------
// adapter 1x1 (one batch): E[i][j][m] = sum_c aw[m][c]*e[i][j][c] + ab[m]  (f32 in, bf16 out)
__global__ __launch_bounds__(256) void adapter_k(const float* __restrict__ e,
                                                 const float* __restrict__ aw,
                                                 const float* __restrict__ ab,
                                                 bf16* __restrict__ E) {
  int i = blockIdx.x;
  int m = threadIdx.x;
  __shared__ float se[256 * 7];
  const size_t rb = (size_t)i * (256 * 7);
  for (int idx = m; idx < 256 * 7; idx += 256) se[idx] = e[rb + idx];
  __syncthreads();
  float w[7];
#pragma unroll
  for (int c = 0; c < 7; ++c) w[c] = aw[m * 7 + c];
  float bias = ab[m];
  bf16* ob = E + (size_t)i * 65536 + m;
  for (int j = 0; j < 256; ++j) {
    const float* ej = se + j * 7;
    float a = bias;
#pragma unroll
    for (int c = 0; c < 7; ++c) a += w[c] * ej[c];
    ob[(size_t)j * 256] = f2b(a);
  }
}

// ---------------------------------------------------------------------------
// node terms: TT[p*3+t][pos][m] = sum_{ot,c} wnp[p][t][ot][c][m]*nd_pad[pos+ot-1][c]
// grid = p(2) x t(3) x chunk(64 of 4 positions) = 384 blocks (was 48 -> 1.98% occupancy)
template <typename T>
__global__ __launch_bounds__(256) void node_terms(const T* __restrict__ nd,
                                                  const bf16* __restrict__ wnp,
                                                  float* __restrict__ TT) {
  int bid = blockIdx.x;
  int chunk = bid & 63;
  int t = (bid >> 6) % 3;
  int p = bid / 192;
  int tid = threadIdx.x;
  __shared__ float snd[6][256];
  int pos0 = chunk * 4;
  for (int idx = tid; idx < 6 * 256; idx += 256) {
    int r = idx >> 8, c = idx & 255;
    int gp = pos0 - 1 + r;
    snd[r][c] = (gp >= 0 && gp < 256) ? (float)nd[(size_t)gp * 256 + c] : 0.f;
  }
  __syncthreads();
  float acc[4] = {0.f, 0.f, 0.f, 0.f};
  const bf16* wb = wnp + (size_t)((p * 3 + t) * 3) * 65536 + tid;
  for (int c = 0; c < 256; ++c) {
    float w0 = b2f(wb[(size_t)c * 256]);
    float w1 = b2f(wb[(size_t)(65536 + c * 256)]);
    float w2 = b2f(wb[(size_t)(2 * 65536 + c * 256)]);
#pragma unroll
    for (int ii = 0; ii < 4; ++ii)   // acc[ii] += w_ot * nd[pos0+ii-1+ot]
      acc[ii] += w0 * snd[ii][c] + w1 * snd[ii + 1][c] + w2 * snd[ii + 2][c];
  }
  float* o = TT + (((size_t)(p * 3 + t) * 256 + pos0) * 256) + tid;
#pragma unroll
  for (int ii = 0; ii < 4; ++ii) o[(size_t)ii * 256] = acc[ii];
}

// ---------------------------------------------------------------------------
// implicit-GEMM 3x3 conv (one batch), 256->256 ch, act [i][j][m] bf16, zero pad.
// EPI: add node terms (+ boundary masks). F32OUT: write f32 (final edge output).
template <int EPI, int F32OUT>
__global__ __launch_bounds__(256, 2)
void conv3x3_k(const bf16* __restrict__ inb, const bf16* __restrict__ wpack,
               const float* __restrict__ bias, void* __restrict__ outv,
               const float* __restrict__ TT, const bf16* __restrict__ zbuf) {
  __shared__ __align__(16) char lB[16384];  // input  [128 px][64 ch] (swizzled)
  __shared__ __align__(16) char lA[16384];  // weight [128 o ][64 ch] (swizzled)
  const int bid = blockIdx.x;               // 1024 = ob(2) * jb(2) * i(256)
  const int ob = bid & 1, jb = (bid >> 1) & 1, i = bid >> 2;
  const int tid = threadIdx.x;
  const int lane = tid & 63, wid = tid >> 6;
  const int wr = wid >> 1, wc = wid & 1;
  const int lo = lane & 15, hi = lane >> 4;

  f32x4 acc[4][4];
  const f32x4 z = {0.f, 0.f, 0.f, 0.f};
#pragma unroll
  for (int mi = 0; mi < 4; ++mi)
#pragma unroll
    for (int ni = 0; ni < 4; ++ni) acc[mi][ni] = z;

  const int xS = tid >> 3;   // staging pixel (row) within 32-row chunk
  const int Gs = tid & 7;    // staging 16B-granule slot
  for (int s = 0; s < 9; ++s) {
    const int ky = s / 3, kx = s - 3 * ky;
    const int r = i + ky - 1;
    if (r < 0 || r > 255) continue;           // block-uniform zero row tap
    const size_t rowbase = (size_t)r * 65536;
    const int colbase = jb * 128 + kx - 1;
    const size_t wbase = ((size_t)s * 256 + ob * 128) * 256;
    for (int cc = 0; cc < 4; ++cc) {
      __syncthreads();                        // prior MFMA reads drained
      const int cb = cc * 64;
#pragma unroll
      for (int ch = 0; ch < 4; ++ch) {
        const int x = ch * 32 + xS;
        const int c = colbase + x;
        const int sw = (Gs ^ (x & 7)) << 3;   // pre-swizzled source granule
        const int ldst = (ch * 256 + wid * 64) << 4;  // wave-uniform LDS dest
        const bf16* srcB = (c >= 0 && c <= 255)
            ? inb + rowbase + ((size_t)c << 8) + cb + sw
            : zbuf + sw;                       // OOB column -> zeros
        gld16(srcB, lB + ldst);
        gld16(wpack + wbase + ((size_t)x << 8) + cb + sw, lA + ldst);
      }
      __syncthreads();                        // staging visible (vmcnt drained)
#pragma unroll
      for (int kk = 0; kk < 2; ++kk) {
        s16x8 af[4], bfr[4];
        const int g0 = kk * 4 + hi;
        const int gx = (g0 ^ (lo & 7)) << 4;
#pragma unroll
        for (int mi = 0; mi < 4; ++mi) {
          const int x = wr * 64 + mi * 16 + lo;
          af[mi] = *(const s16x8*)(lB + x * 128 + gx);
        }
#pragma unroll
        for (int ni = 0; ni < 4; ++ni) {
          const int x = wc * 64 + ni * 16 + lo;
          bfr[ni] = *(const s16x8*)(lA + x * 128 + gx);
        }
#pragma unroll
        for (int mi = 0; mi < 4; ++mi)
#pragma unroll
          for (int ni = 0; ni < 4; ++ni)
            acc[mi][ni] = __builtin_amdgcn_mfma_f32_16x16x32_bf16(af[mi], bfr[ni], acc[mi][ni], 0, 0, 0);
      }
    }
  }

  // epilogue: D col(lane&15)->o, row((lane>>4)*4+r)->pixel j
  const int o_base = ob * 128 + wc * 64 + lo;
  const int j_base = jb * 128 + wr * 64 + hi * 4;
  bf16* orow = (bf16*)outv + (size_t)i * 65536;
  float* orowf = (float*)outv + (size_t)i * 65536;
#pragma unroll
  for (int ni = 0; ni < 4; ++ni) {
    const int o = o_base + ni * 16;
    const float bs = bias[o];
    float ni0 = 0.f, ni1 = 0.f, ni2 = 0.f;
    if (EPI) {
      const float* TI = TT + (size_t)i * 256 + o;     // p=0 (node_i), t=kx
      ni0 = TI[0]; ni1 = TI[65536]; ni2 = TI[2 * 65536];
    }
#pragma unroll
    for (int mi = 0; mi < 4; ++mi) {
#pragma unroll
      for (int r = 0; r < 4; ++r) {
        const int j = j_base + mi * 16 + r;
        float v = acc[mi][ni][r] + bs;
        if (EPI) {
          v += ni1 + (j > 0 ? ni0 : 0.f) + (j < 255 ? ni2 : 0.f);
          const float* TJ = TT + (size_t)3 * 65536 + (size_t)j * 256 + o;  // p=1, t=ky
          float nj0 = TJ[0], nj1 = TJ[65536], nj2 = TJ[2 * 65536];
          v += nj1 + (i > 0 ? nj0 : 0.f) + (i < 255 ? nj2 : 0.f);
        }
        v = fmaxf(v, 0.f);
        if (F32OUT) orowf[(size_t)j * 256 + o] = v;
        else        orow[(size_t)j * 256 + o] = f2b(v);
      }
    }
  }
}

// ---------------------------------------------------------------------------
// fused: att = leaky(1x1(feat)); coeff = softmax_j; nd[i][m] = sum_j coeff*feat
// F32OUT: write f32 final node output, else bf16 ND scratch.
template <int F32OUT>
__global__ __launch_bounds__(256) void att_wsum(const bf16* __restrict__ feat,
                                                const float* __restrict__ aw,
                                                const float* __restrict__ ab,
                                                bf16* __restrict__ ndb,
                                                float* __restrict__ ndf) {
  int i = blockIdx.x;
  int tid = threadIdx.x, lane = tid & 63, w = tid >> 6;
  __shared__ float s_aw[256];
  __shared__ float s_att[256];
  __shared__ float s_red[8];
  s_aw[tid] = aw[tid];
  __syncthreads();
  float a0 = s_aw[lane * 4], a1 = s_aw[lane * 4 + 1];
  float a2 = s_aw[lane * 4 + 2], a3 = s_aw[lane * 4 + 3];
  const bf16* fb = feat + (size_t)i * 65536;
  float abv = ab[0];
  for (int jj = 0; jj < 64; ++jj) {
    int j = w * 64 + jj;
    const bf16* f = fb + (size_t)j * 256 + lane * 4;
    float v = a0 * b2f(f[0]) + a1 * b2f(f[1]) + a2 * b2f(f[2]) + a3 * b2f(f[3]);
#pragma unroll
    for (int mk = 32; mk; mk >>= 1) v += __shfl_xor(v, mk);
    if (lane == 0) { float a = v + abv; s_att[j] = a > 0.f ? a : 0.01f * a; }
  }
  __syncthreads();
  float x = s_att[tid];
  float mx = x;
#pragma unroll
  for (int mk = 32; mk; mk >>= 1) mx = fmaxf(mx, __shfl_xor(mx, mk));
  if (lane == 0) s_red[w] = mx;
  __syncthreads();
  mx = fmaxf(fmaxf(s_red[0], s_red[1]), fmaxf(s_red[2], s_red[3]));
  float e = expf(x - mx);
  float sm = e;
#pragma unroll
  for (int mk = 32; mk; mk >>= 1) sm += __shfl_xor(sm, mk);
  if (lane == 0) s_red[4 + w] = sm;
  __syncthreads();
  sm = s_red[4] + s_red[5] + s_red[6] + s_red[7];
  __syncthreads();
  s_att[tid] = e / sm;
  __syncthreads();
  float acc = 0.f;
  for (int j = 0; j < 256; ++j) acc += s_att[j] * b2f(fb[(size_t)j * 256 + tid]);
  if (F32OUT) ndf[(size_t)i * 256 + tid] = acc;
  else        ndb[(size_t)i * 256 + tid] = f2b(acc);
}

// ---------------------------------------------------------------------------
extern "C" void kernel_launch(void* const* d_in, const int* in_sizes, int n_in,
                              void* d_out, int out_size, void* d_ws, size_t ws_size,
                              hipStream_t stream) {
  const float* edge_feats = (const float*)d_in[0];
  const float* node_feats = (const float*)d_in[1];
  const float* adapter_w  = (const float*)d_in[2];
  const float* adapter_b  = (const float*)d_in[3];
  const float* conv0_w    = (const float*)d_in[4];
  const float* conv0_b    = (const float*)d_in[5];
  const float* conv1_w    = (const float*)d_in[6];
  const float* conv1_b    = (const float*)d_in[7];
  const float* last_w     = (const float*)d_in[8];
  const float* last_b     = (const float*)d_in[9];
  const float* att_w      = (const float*)d_in[10];
  const float* att_b      = (const float*)d_in[11];
  float* out = (float*)d_out;

  char* ws = (char*)d_ws;
  size_t off = 0;
  bf16* Q   = (bf16*)(ws + off); off += (size_t)256 * 256 * 256 * 2;      // 33,554,432
  bf16* WP0 = (bf16*)(ws + off); off += (size_t)9 * 65536 * 2;
  bf16* WP1 = (bf16*)(ws + off); off += (size_t)9 * 65536 * 2;
  bf16* WP2 = (bf16*)(ws + off); off += (size_t)9 * 65536 * 2;
  bf16* WNP = (bf16*)(ws + off); off += (size_t)18 * 65536 * 2;           //  2,359,296
  float* TT = (float*)(ws + off); off += (size_t)2 * 3 * 65536 * 4;       //  1,572,864
  bf16* ND  = (bf16*)(ws + off); off += (size_t)65536 * 2;                //    131,072
  bf16* ZB  = (bf16*)(ws + off); off += 256;                              // known-safe total 41,156,864
  if (ws_size < off) {
    fill_sentinel<<<(out_size + 255) / 256, 256, 0, stream>>>(out, out_size);
    return;
  }

  zero_zb<<<1, 64, 0, stream>>>(ZB);
  pack_w<<<11520, 256, 0, stream>>>(conv0_w, conv1_w, last_w, WP0, WP1, WP2, WNP);

  for (int b = 0; b < 2; ++b) {
    // P: bf16 scratch inside the (f32) edge-out region of batch b (first 32MB of 64MB)
    bf16* P = (bf16*)(out + 131072 + (size_t)b * 16777216);
    float* edge_out = out + 131072 + (size_t)b * 16777216;
    float* node_out = out + (size_t)b * 65536;
    const float* eb = edge_feats + (size_t)b * 458752;
    const float* nb = node_feats + (size_t)b * 65536;

    adapter_k<<<256, 256, 0, stream>>>(eb, adapter_w, adapter_b, P);                  // E  @ P
    // block 1
    node_terms<float><<<384, 256, 0, stream>>>(nb, WNP, TT);
    conv3x3_k<1, 0><<<1024, 256, 0, stream>>>(P, WP0, conv0_b, Q, TT, ZB);            // A  @ Q
    conv3x3_k<0, 0><<<1024, 256, 0, stream>>>(Q, WP1, conv1_b, P, nullptr, ZB);       // B  @ P
    att_wsum<0><<<256, 256, 0, stream>>>(P, att_w, att_b, ND, nullptr);               // nd1 @ ND
    conv3x3_k<0, 0><<<1024, 256, 0, stream>>>(P, WP2, last_b, Q, nullptr, ZB);        // C  @ Q
    // block 2
    node_terms<bf16><<<384, 256, 0, stream>>>(ND, WNP, TT);
    conv3x3_k<1, 0><<<1024, 256, 0, stream>>>(Q, WP0, conv0_b, P, TT, ZB);            // D  @ P
    conv3x3_k<0, 0><<<1024, 256, 0, stream>>>(P, WP1, conv1_b, Q, nullptr, ZB);       // E2 @ Q
    att_wsum<1><<<256, 256, 0, stream>>>(Q, att_w, att_b, nullptr, node_out);         // node out (f32)
    conv3x3_k<0, 1><<<1024, 256, 0, stream>>>(Q, WP2, last_b, edge_out, nullptr, ZB); // edge out (f32)
  }
}

// Round 6
// 1256.298 us; speedup vs baseline: 1.4587x; 1.1972x over previous
//
#include <hip/hip_runtime.h>
#include <hip/hip_bf16.h>

typedef __hip_bfloat16 bf16;
typedef __attribute__((ext_vector_type(8))) short s16x8;   // 8 bf16 (4 VGPR) MFMA A/B frag
typedef __attribute__((ext_vector_type(4))) float f32x4;   // MFMA C/D frag

__device__ __forceinline__ float b2f(bf16 x) { return __bfloat162float(x); }
__device__ __forceinline__ bf16 f2b(float x) { return __float2bfloat16(x); }

__device__ __forceinline__ void gld16(const void* g, void* l) {
  __builtin_amdgcn_global_load_lds((const __attribute__((address_space(1))) unsigned int*)g,
                                   (__attribute__((address_space(3))) unsigned int*)l,
                                   16, 0, 0);
}

// ---------------------------------------------------------------------------
// sentinel: unmistakable absmax if workspace too small (f32 out)
__global__ __launch_bounds__(256) void fill_sentinel(float* out, int n) {
  int idx = blockIdx.x * 256 + threadIdx.x;
  if (idx < n) out[idx] = 100.0f;
}

__global__ __launch_bounds__(64) void zero_zb(bf16* zb) {
  zb[threadIdx.x * 2] = f2b(0.f);
  zb[threadIdx.x * 2 + 1] = f2b(0.f);
}

// ---------------------------------------------------------------------------
// pack conv weights (f32 -> bf16): wpN[s][o][c]; wnp[p][t][ot][c][m]
__global__ __launch_bounds__(256) void pack_w(const float* __restrict__ c0w,
                                              const float* __restrict__ c1w,
                                              const float* __restrict__ lw,
                                              bf16* wp0, bf16* wp1, bf16* wp2, bf16* wnp) {
  const int SEG = 9 * 256 * 256;
  int idx = blockIdx.x * 256 + threadIdx.x;
  if (idx < 3 * SEG) {
    int which = idx / SEG, r = idx % SEG;
    int s = r >> 16, o = (r >> 8) & 255, c = r & 255;
    int ky = s / 3, kx = s - 3 * ky;
    if (which == 0)      wp0[r] = f2b(c0w[(((size_t)o * 768 + 256 + c) * 3 + ky) * 3 + kx]);
    else if (which == 1) wp1[r] = f2b(c1w[(((size_t)o * 256 + c) * 3 + ky) * 3 + kx]);
    else                 wp2[r] = f2b(lw [(((size_t)o * 256 + c) * 3 + ky) * 3 + kx]);
  } else {
    int r = idx - 3 * SEG;             // [p][t][ot][c][m]
    int m = r & 255, c = (r >> 8) & 255, tt = r >> 16;
    int ot = tt % 3, t2 = (tt / 3) % 3, p = tt / 9;
    int ky, kx, cin;
    if (p == 0) { kx = t2; ky = ot; cin = c; }        // node_i block
    else        { ky = t2; kx = ot; cin = 512 + c; }  // node_j block
    wnp[r] = f2b(c0w[(((size_t)m * 768 + cin) * 3 + ky) * 3 + kx]);
  }
}

// ---------------------------------------------------------------------------
// adapter 1x1 (one batch): E[i][j][m] = sum_c aw[m][c]*e[i][j][c] + ab[m]  (f32 in, bf16 out)
__global__ __launch_bounds__(256) void adapter_k(const float* __restrict__ e,
                                                 const float* __restrict__ aw,
                                                 const float* __restrict__ ab,
                                                 bf16* __restrict__ E) {
  int i = blockIdx.x;
  int m = threadIdx.x;
  __shared__ float se[256 * 7];
  const size_t rb = (size_t)i * (256 * 7);
  for (int idx = m; idx < 256 * 7; idx += 256) se[idx] = e[rb + idx];
  __syncthreads();
  float w[7];
#pragma unroll
  for (int c = 0; c < 7; ++c) w[c] = aw[m * 7 + c];
  float bias = ab[m];
  bf16* ob = E + (size_t)i * 65536 + m;
  for (int j = 0; j < 256; ++j) {
    const float* ej = se + j * 7;
    float a = bias;
#pragma unroll
    for (int c = 0; c < 7; ++c) a += w[c] * ej[c];
    ob[(size_t)j * 256] = f2b(a);
  }
}

// ---------------------------------------------------------------------------
// node terms: TT[p*3+t][pos][m] = sum_{ot,c} wnp[p][t][ot][c][m]*nd_pad[pos+ot-1][c]
// grid = p(2) x t(3) x chunk(64 of 4 positions) = 384 blocks
template <typename T>
__global__ __launch_bounds__(256) void node_terms(const T* __restrict__ nd,
                                                  const bf16* __restrict__ wnp,
                                                  float* __restrict__ TT) {
  int bid = blockIdx.x;
  int chunk = bid & 63;
  int t = (bid >> 6) % 3;
  int p = bid / 192;
  int tid = threadIdx.x;
  __shared__ float snd[6][256];
  int pos0 = chunk * 4;
  for (int idx = tid; idx < 6 * 256; idx += 256) {
    int r = idx >> 8, c = idx & 255;
    int gp = pos0 - 1 + r;
    snd[r][c] = (gp >= 0 && gp < 256) ? (float)nd[(size_t)gp * 256 + c] : 0.f;
  }
  __syncthreads();
  float acc[4] = {0.f, 0.f, 0.f, 0.f};
  const bf16* wb = wnp + (size_t)((p * 3 + t) * 3) * 65536 + tid;
  for (int c = 0; c < 256; ++c) {
    float w0 = b2f(wb[(size_t)c * 256]);
    float w1 = b2f(wb[(size_t)(65536 + c * 256)]);
    float w2 = b2f(wb[(size_t)(2 * 65536 + c * 256)]);
#pragma unroll
    for (int ii = 0; ii < 4; ++ii)   // acc[ii] += w_ot * nd[pos0+ii-1+ot]
      acc[ii] += w0 * snd[ii][c] + w1 * snd[ii + 1][c] + w2 * snd[ii + 2][c];
  }
  float* o = TT + (((size_t)(p * 3 + t) * 256 + pos0) * 256) + tid;
#pragma unroll
  for (int ii = 0; ii < 4; ++ii) o[(size_t)ii * 256] = acc[ii];
}

// ---------------------------------------------------------------------------
// implicit-GEMM 3x3 conv (one batch), 256->256 ch, act [i][j][m] bf16, zero pad.
// EPI: add node terms (+ boundary masks). F32OUT: write f32 (final edge output).
// XCD-aware swizzle: HW maps bid -> XCD round-robin (bid & 7); give each XCD a
// contiguous 32-row i-band so the 6x re-reads (3 ky taps x 2 ob halves) of each
// input row hit that XCD's private 4MB L2 instead of HBM (was 254 MB fetch/disp).
template <int EPI, int F32OUT>
__global__ __launch_bounds__(256, 4)
void conv3x3_k(const bf16* __restrict__ inb, const bf16* __restrict__ wpack,
               const float* __restrict__ bias, void* __restrict__ outv,
               const float* __restrict__ TT, const bf16* __restrict__ zbuf) {
  __shared__ __align__(16) char lB[16384];  // input  [128 px][64 ch] (swizzled)
  __shared__ __align__(16) char lA[16384];  // weight [128 o ][64 ch] (swizzled)
  const int bid = blockIdx.x;               // 1024 = xcd(8) x slot(128)
  const int xcd = bid & 7, slot = bid >> 3;
  const int i = (xcd << 5) + (slot >> 2);   // 32-row band per XCD
  const int ob = slot & 1, jb = (slot >> 1) & 1;
  const int tid = threadIdx.x;
  const int lane = tid & 63, wid = tid >> 6;
  const int wr = wid >> 1, wc = wid & 1;
  const int lo = lane & 15, hi = lane >> 4;

  f32x4 acc[4][4];
  const f32x4 z = {0.f, 0.f, 0.f, 0.f};
#pragma unroll
  for (int mi = 0; mi < 4; ++mi)
#pragma unroll
    for (int ni = 0; ni < 4; ++ni) acc[mi][ni] = z;

  const int xS = tid >> 3;   // staging pixel (row) within 32-row chunk
  const int Gs = tid & 7;    // staging 16B-granule slot
  for (int s = 0; s < 9; ++s) {
    const int ky = s / 3, kx = s - 3 * ky;
    const int r = i + ky - 1;
    if (r < 0 || r > 255) continue;           // block-uniform zero row tap
    const size_t rowbase = (size_t)r * 65536;
    const int colbase = jb * 128 + kx - 1;
    const size_t wbase = ((size_t)s * 256 + ob * 128) * 256;
    for (int cc = 0; cc < 4; ++cc) {
      __syncthreads();                        // prior MFMA reads drained
      const int cb = cc * 64;
#pragma unroll
      for (int ch = 0; ch < 4; ++ch) {
        const int x = ch * 32 + xS;
        const int c = colbase + x;
        const int sw = (Gs ^ (x & 7)) << 3;   // pre-swizzled source granule
        const int ldst = (ch * 256 + wid * 64) << 4;  // wave-uniform LDS dest
        const bf16* srcB = (c >= 0 && c <= 255)
            ? inb + rowbase + ((size_t)c << 8) + cb + sw
            : zbuf + sw;                       // OOB column -> zeros
        gld16(srcB, lB + ldst);
        gld16(wpack + wbase + ((size_t)x << 8) + cb + sw, lA + ldst);
      }
      __syncthreads();                        // staging visible (vmcnt drained)
#pragma unroll
      for (int kk = 0; kk < 2; ++kk) {
        s16x8 af[4], bfr[4];
        const int g0 = kk * 4 + hi;
        const int gx = (g0 ^ (lo & 7)) << 4;
#pragma unroll
        for (int mi = 0; mi < 4; ++mi) {
          const int x = wr * 64 + mi * 16 + lo;
          af[mi] = *(const s16x8*)(lB + x * 128 + gx);
        }
#pragma unroll
        for (int ni = 0; ni < 4; ++ni) {
          const int x = wc * 64 + ni * 16 + lo;
          bfr[ni] = *(const s16x8*)(lA + x * 128 + gx);
        }
#pragma unroll
        for (int mi = 0; mi < 4; ++mi)
#pragma unroll
          for (int ni = 0; ni < 4; ++ni)
            acc[mi][ni] = __builtin_amdgcn_mfma_f32_16x16x32_bf16(af[mi], bfr[ni], acc[mi][ni], 0, 0, 0);
      }
    }
  }

  // epilogue: D col(lane&15)->o, row((lane>>4)*4+r)->pixel j
  const int o_base = ob * 128 + wc * 64 + lo;
  const int j_base = jb * 128 + wr * 64 + hi * 4;
  bf16* orow = (bf16*)outv + (size_t)i * 65536;
  float* orowf = (float*)outv + (size_t)i * 65536;
#pragma unroll
  for (int ni = 0; ni < 4; ++ni) {
    const int o = o_base + ni * 16;
    const float bs = bias[o];
    float ni0 = 0.f, ni1 = 0.f, ni2 = 0.f;
    if (EPI) {
      const float* TI = TT + (size_t)i * 256 + o;     // p=0 (node_i), t=kx
      ni0 = TI[0]; ni1 = TI[65536]; ni2 = TI[2 * 65536];
    }
#pragma unroll
    for (int mi = 0; mi < 4; ++mi) {
#pragma unroll
      for (int r = 0; r < 4; ++r) {
        const int j = j_base + mi * 16 + r;
        float v = acc[mi][ni][r] + bs;
        if (EPI) {
          v += ni1 + (j > 0 ? ni0 : 0.f) + (j < 255 ? ni2 : 0.f);
          const float* TJ = TT + (size_t)3 * 65536 + (size_t)j * 256 + o;  // p=1, t=ky
          float nj0 = TJ[0], nj1 = TJ[65536], nj2 = TJ[2 * 65536];
          v += nj1 + (i > 0 ? nj0 : 0.f) + (i < 255 ? nj2 : 0.f);
        }
        v = fmaxf(v, 0.f);
        if (F32OUT) orowf[(size_t)j * 256 + o] = v;
        else        orow[(size_t)j * 256 + o] = f2b(v);
      }
    }
  }
}

// ---------------------------------------------------------------------------
// fused: att = leaky(1x1(feat)); coeff = softmax_j; nd[i][m] = sum_j coeff*feat
// F32OUT: write f32 final node output, else bf16 ND scratch.
template <int F32OUT>
__global__ __launch_bounds__(256) void att_wsum(const bf16* __restrict__ feat,
                                                const float* __restrict__ aw,
                                                const float* __restrict__ ab,
                                                bf16* __restrict__ ndb,
                                                float* __restrict__ ndf) {
  int i = blockIdx.x;
  int tid = threadIdx.x, lane = tid & 63, w = tid >> 6;
  __shared__ float s_aw[256];
  __shared__ float s_att[256];
  __shared__ float s_red[8];
  s_aw[tid] = aw[tid];
  __syncthreads();
  float a0 = s_aw[lane * 4], a1 = s_aw[lane * 4 + 1];
  float a2 = s_aw[lane * 4 + 2], a3 = s_aw[lane * 4 + 3];
  const bf16* fb = feat + (size_t)i * 65536;
  float abv = ab[0];
  for (int jj = 0; jj < 64; ++jj) {
    int j = w * 64 + jj;
    const bf16* f = fb + (size_t)j * 256 + lane * 4;
    float v = a0 * b2f(f[0]) + a1 * b2f(f[1]) + a2 * b2f(f[2]) + a3 * b2f(f[3]);
#pragma unroll
    for (int mk = 32; mk; mk >>= 1) v += __shfl_xor(v, mk);
    if (lane == 0) { float a = v + abv; s_att[j] = a > 0.f ? a : 0.01f * a; }
  }
  __syncthreads();
  float x = s_att[tid];
  float mx = x;
#pragma unroll
  for (int mk = 32; mk; mk >>= 1) mx = fmaxf(mx, __shfl_xor(mx, mk));
  if (lane == 0) s_red[w] = mx;
  __syncthreads();
  mx = fmaxf(fmaxf(s_red[0], s_red[1]), fmaxf(s_red[2], s_red[3]));
  float e = expf(x - mx);
  float sm = e;
#pragma unroll
  for (int mk = 32; mk; mk >>= 1) sm += __shfl_xor(sm, mk);
  if (lane == 0) s_red[4 + w] = sm;
  __syncthreads();
  sm = s_red[4] + s_red[5] + s_red[6] + s_red[7];
  __syncthreads();
  s_att[tid] = e / sm;
  __syncthreads();
  float acc = 0.f;
  for (int j = 0; j < 256; ++j) acc += s_att[j] * b2f(fb[(size_t)j * 256 + tid]);
  if (F32OUT) ndf[(size_t)i * 256 + tid] = acc;
  else        ndb[(size_t)i * 256 + tid] = f2b(acc);
}

// ---------------------------------------------------------------------------
extern "C" void kernel_launch(void* const* d_in, const int* in_sizes, int n_in,
                              void* d_out, int out_size, void* d_ws, size_t ws_size,
                              hipStream_t stream) {
  const float* edge_feats = (const float*)d_in[0];
  const float* node_feats = (const float*)d_in[1];
  const float* adapter_w  = (const float*)d_in[2];
  const float* adapter_b  = (const float*)d_in[3];
  const float* conv0_w    = (const float*)d_in[4];
  const float* conv0_b    = (const float*)d_in[5];
  const float* conv1_w    = (const float*)d_in[6];
  const float* conv1_b    = (const float*)d_in[7];
  const float* last_w     = (const float*)d_in[8];
  const float* last_b     = (const float*)d_in[9];
  const float* att_w      = (const float*)d_in[10];
  const float* att_b      = (const float*)d_in[11];
  float* out = (float*)d_out;

  char* ws = (char*)d_ws;
  size_t off = 0;
  bf16* Q   = (bf16*)(ws + off); off += (size_t)256 * 256 * 256 * 2;      // 33,554,432
  bf16* WP0 = (bf16*)(ws + off); off += (size_t)9 * 65536 * 2;
  bf16* WP1 = (bf16*)(ws + off); off += (size_t)9 * 65536 * 2;
  bf16* WP2 = (bf16*)(ws + off); off += (size_t)9 * 65536 * 2;
  bf16* WNP = (bf16*)(ws + off); off += (size_t)18 * 65536 * 2;           //  2,359,296
  float* TT = (float*)(ws + off); off += (size_t)2 * 3 * 65536 * 4;       //  1,572,864
  bf16* ND  = (bf16*)(ws + off); off += (size_t)65536 * 2;                //    131,072
  bf16* ZB  = (bf16*)(ws + off); off += 256;                              // known-safe total 41,156,864
  if (ws_size < off) {
    fill_sentinel<<<(out_size + 255) / 256, 256, 0, stream>>>(out, out_size);
    return;
  }

  zero_zb<<<1, 64, 0, stream>>>(ZB);
  pack_w<<<11520, 256, 0, stream>>>(conv0_w, conv1_w, last_w, WP0, WP1, WP2, WNP);

  for (int b = 0; b < 2; ++b) {
    // P: bf16 scratch inside the (f32) edge-out region of batch b (first 32MB of 64MB)
    bf16* P = (bf16*)(out + 131072 + (size_t)b * 16777216);
    float* edge_out = out + 131072 + (size_t)b * 16777216;
    float* node_out = out + (size_t)b * 65536;
    const float* eb = edge_feats + (size_t)b * 458752;
    const float* nb = node_feats + (size_t)b * 65536;

    adapter_k<<<256, 256, 0, stream>>>(eb, adapter_w, adapter_b, P);                  // E  @ P
    // block 1
    node_terms<float><<<384, 256, 0, stream>>>(nb, WNP, TT);
    conv3x3_k<1, 0><<<1024, 256, 0, stream>>>(P, WP0, conv0_b, Q, TT, ZB);            // A  @ Q
    conv3x3_k<0, 0><<<1024, 256, 0, stream>>>(Q, WP1, conv1_b, P, nullptr, ZB);       // B  @ P
    att_wsum<0><<<256, 256, 0, stream>>>(P, att_w, att_b, ND, nullptr);               // nd1 @ ND
    conv3x3_k<0, 0><<<1024, 256, 0, stream>>>(P, WP2, last_b, Q, nullptr, ZB);        // C  @ Q
    // block 2
    node_terms<bf16><<<384, 256, 0, stream>>>(ND, WNP, TT);
    conv3x3_k<1, 0><<<1024, 256, 0, stream>>>(Q, WP0, conv0_b, P, TT, ZB);            // D  @ P
    conv3x3_k<0, 0><<<1024, 256, 0, stream>>>(P, WP1, conv1_b, Q, nullptr, ZB);       // E2 @ Q
    att_wsum<1><<<256, 256, 0, stream>>>(Q, att_w, att_b, nullptr, node_out);         // node out (f32)
    conv3x3_k<0, 1><<<1024, 256, 0, stream>>>(Q, WP2, last_b, edge_out, nullptr, ZB); // edge out (f32)
  }
}